// Round 13
// baseline (325.195 us; speedup 1.0000x reference)
//
#include <hip/hip_runtime.h>
#include <hip/hip_bf16.h>

#define SQ 2048
#define SK 2048
#define DD 128
#define NBH 32
#define QBLK 64
#define KBLK 32
#define NKT (SK / KBLK)
#define SCALE 0.20884964425119185f
#define SCL2 (SCALE * 1.4426950408889634f)   // fold log2(e): exp2

typedef __attribute__((ext_vector_type(8))) short short8;
typedef __attribute__((ext_vector_type(4))) float f32x4;
typedef __attribute__((ext_vector_type(4))) unsigned int u32x4;

#define KIMG 8192
// f32 fallback LDS (R9-proven layout)
#define KPITCH 272
#define VPITCH 80
#define VOFF_F 8704
#define SMEM_F32 18944

static __device__ __forceinline__ unsigned int pk_bf16(float lo, float hi) {
    float2 f2; f2.x = lo; f2.y = hi;
    __hip_bfloat162 h = __float22bfloat162_rn(f2);   // v_cvt_pk_bf16_f32
    union { __hip_bfloat162 h2; unsigned int u; } cv; cv.h2 = h;
    return cv.u;
}

// natural-order softmax (R12-verified): P feeds PV A-operand directly
// (k-permutation baked into the V image; MFMA k-sum is permutation-invariant)
#define SOFTMAX_NAT(PA, SA_, SB_, MCa, MCb, LPART)                             \
  { float p_[8];                                                               \
    p_[0] = __builtin_amdgcn_exp2f(SA_[0]*SCL2);                               \
    p_[1] = __builtin_amdgcn_exp2f(SA_[1]*SCL2);                               \
    p_[2] = __builtin_amdgcn_exp2f(SA_[2]*SCL2);                               \
    p_[3] = __builtin_amdgcn_exp2f(SA_[3]*SCL2);                               \
    p_[4] = __builtin_amdgcn_exp2f(SB_[0]*SCL2);                               \
    p_[5] = __builtin_amdgcn_exp2f(SB_[1]*SCL2);                               \
    p_[6] = __builtin_amdgcn_exp2f(SB_[2]*SCL2);                               \
    p_[7] = __builtin_amdgcn_exp2f(SB_[3]*SCL2);                               \
    LPART += ((p_[0]+p_[1]) + (p_[2]+p_[3])) + ((p_[4]+p_[5]) + (p_[6]+p_[7]));\
    p_[0]*=MCa.x; p_[1]*=MCa.y; p_[2]*=MCa.z; p_[3]*=MCa.w;                    \
    p_[4]*=MCb.x; p_[5]*=MCb.y; p_[6]*=MCb.z; p_[7]*=MCb.w;                    \
    union { unsigned int u[4]; short8 v; } pb_;                                \
    pb_.u[0] = pk_bf16(p_[0],p_[1]); pb_.u[1] = pk_bf16(p_[2],p_[3]);          \
    pb_.u[2] = pk_bf16(p_[4],p_[5]); pb_.u[3] = pk_bf16(p_[6],p_[7]);          \
    PA = pb_.v; }

// f32 fallback keeps the shfl-redistribution (R3..R9-proven)
#define SOFTMAX_PACK(PA, SA_, SB_, MCa, MCb, LPART)                            \
  { float p_[8];                                                               \
    p_[0] = __builtin_amdgcn_exp2f(SA_[0]*SCL2);                               \
    p_[1] = __builtin_amdgcn_exp2f(SA_[1]*SCL2);                               \
    p_[2] = __builtin_amdgcn_exp2f(SA_[2]*SCL2);                               \
    p_[3] = __builtin_amdgcn_exp2f(SA_[3]*SCL2);                               \
    p_[4] = __builtin_amdgcn_exp2f(SB_[0]*SCL2);                               \
    p_[5] = __builtin_amdgcn_exp2f(SB_[1]*SCL2);                               \
    p_[6] = __builtin_amdgcn_exp2f(SB_[2]*SCL2);                               \
    p_[7] = __builtin_amdgcn_exp2f(SB_[3]*SCL2);                               \
    LPART += ((p_[0]+p_[1]) + (p_[2]+p_[3])) + ((p_[4]+p_[5]) + (p_[6]+p_[7]));\
    p_[0]*=MCa.x; p_[1]*=MCa.y; p_[2]*=MCa.z; p_[3]*=MCa.w;                    \
    p_[4]*=MCb.x; p_[5]*=MCb.y; p_[6]*=MCb.z; p_[7]*=MCb.w;                    \
    unsigned int P0 = pk_bf16(p_[0],p_[1]), P1 = pk_bf16(p_[2],p_[3]);         \
    unsigned int P2 = pk_bf16(p_[4],p_[5]), P3 = pk_bf16(p_[6],p_[7]);         \
    unsigned int a0 = __shfl((int)P0, sA), a2 = __shfl((int)P2, sA);           \
    unsigned int b0 = __shfl((int)P1, sA), b2 = __shfl((int)P3, sA);           \
    unsigned int c0 = __shfl((int)P0, sB), c2 = __shfl((int)P2, sB);           \
    unsigned int d0 = __shfl((int)P1, sB), d2 = __shfl((int)P3, sB);           \
    union { unsigned int u[4]; short8 v; } pb_;                                \
    pb_.u[0] = hi ? a2 : a0; pb_.u[1] = hi ? b2 : b0;                          \
    pb_.u[2] = hi ? c2 : c0; pb_.u[3] = hi ? d2 : d0;                          \
    PA = pb_.v; }

#define BAR()                                                                  \
    asm volatile("s_waitcnt lgkmcnt(0)" ::: "memory");                         \
    __builtin_amdgcn_sched_barrier(0);                                         \
    __builtin_amdgcn_s_barrier();                                              \
    __builtin_amdgcn_sched_barrier(0);

// one K-tile, barrier-free: issue vf(t) | QK from kf regs | issue kf(t+1) |
// softmax(mask t) + issue mask(t+1) | PV with vf
#define BODY_BF(MC0, MC1, MN0, MN1, KT)                                        \
  { const size_t tb  = (size_t)(KT) * KIMG;                                    \
    const size_t tbn = (size_t)(((KT) < NKT - 1) ? (KT) + 1 : (KT)) * KIMG;    \
    _Pragma("unroll")                                                          \
    for (int d8 = 0; d8 < 8; ++d8)                                             \
      vf[d8] = *(const short8*)(vbase + tb + d8 * 1024);                       \
    f32x4 s00 = {0,0,0,0}, s01 = {0,0,0,0};                                    \
    __builtin_amdgcn_s_setprio(1);                                             \
    _Pragma("unroll")                                                          \
    for (int ks = 0; ks < 4; ++ks) {                                           \
      s00 = __builtin_amdgcn_mfma_f32_16x16x32_bf16(kf[2*ks],   qf[ks], s00, 0,0,0); \
      s01 = __builtin_amdgcn_mfma_f32_16x16x32_bf16(kf[2*ks+1], qf[ks], s01, 0,0,0); \
    }                                                                          \
    __builtin_amdgcn_s_setprio(0);                                             \
    _Pragma("unroll")                                                          \
    for (int f = 0; f < 8; ++f)                                                \
      kf[f] = *(const short8*)(kbase + tbn + f * 1024);                        \
    MN0 = *(const float4*)(mq0 + (((KT) < NKT - 1) ? (KT) + 1 : (KT)) * KBLK); \
    MN1 = *(const float4*)(mq0 + (((KT) < NKT - 1) ? (KT) + 1 : (KT)) * KBLK + 16); \
    short8 pa;                                                                 \
    SOFTMAX_NAT(pa, s00, s01, MC0, MC1, lp)                                    \
    __builtin_amdgcn_s_setprio(1);                                             \
    _Pragma("unroll")                                                          \
    for (int d8 = 0; d8 < 8; ++d8)                                             \
      o[d8] = __builtin_amdgcn_mfma_f32_16x16x32_bf16(pa, vf[d8], o[d8], 0,0,0); \
    __builtin_amdgcn_s_setprio(0);                                             \
  }

#define KERNEL_PRE()                                                           \
    const int tid  = threadIdx.x;                                              \
    const int lane = tid & 63, wid = tid >> 6;                                 \
    const int c = lane & 15, g = lane >> 4;                                    \
    const int bid = blockIdx.x;                                                \
    const int swz = (bid & 7) * 128 + (bid >> 3);  /* 1024 = 128 x 8, bijective */\
    const int bh = swz >> 5;                                                   \
    const int qb = swz & 31;                                                   \
    const float* x1b = x1 + ((size_t)bh * SQ + (size_t)qb * QBLK) * DD;        \
    const float* mb  = mask + ((size_t)bh * SQ + (size_t)qb * QBLK) * SK;      \
    float*      outb = out + ((size_t)bh * SQ + (size_t)qb * QBLK) * DD;       \
    const float* mq0 = mb + (size_t)(wid*16 + c) * SK + 4*g;

#define KERNEL_QLOAD()                                                         \
    short8 qf[4];                                                              \
    {  const float* q0r = x1b + (size_t)(wid*16 + c) * DD;                     \
       _Pragma("unroll")                                                       \
       for (int ks = 0; ks < 4; ++ks) {                                        \
           float4 a = *(const float4*)(q0r + ks*32 + 8*g);                     \
           float4 b = *(const float4*)(q0r + ks*32 + 8*g + 4);                 \
           union { unsigned int u[4]; short8 s; } t;                           \
           t.u[0]=pk_bf16(a.x,a.y); t.u[1]=pk_bf16(a.z,a.w);                   \
           t.u[2]=pk_bf16(b.x,b.y); t.u[3]=pk_bf16(b.z,b.w);                   \
           qf[ks]=t.s;                                                         \
       } }

#define KERNEL_EPILOGUE()                                                      \
    float l = lp; l += __shfl_xor(l, 16); l += __shfl_xor(l, 32);              \
    float il0 = 1.0f/__shfl(l, 4*g+0), il1 = 1.0f/__shfl(l, 4*g+1);            \
    float il2 = 1.0f/__shfl(l, 4*g+2), il3 = 1.0f/__shfl(l, 4*g+3);            \
    float* orow = outb + (size_t)(wid*16) * DD;                                \
    _Pragma("unroll")                                                          \
    for (int d8 = 0; d8 < 8; ++d8) {                                           \
        orow[(4*g + 0) * DD + d8*16 + c] = o[d8][0] * il0;                     \
        orow[(4*g + 1) * DD + d8*16 + c] = o[d8][1] * il1;                     \
        orow[(4*g + 2) * DD + d8*16 + c] = o[d8][2] * il2;                     \
        orow[(4*g + 3) * DD + d8*16 + c] = o[d8][3] * il3;                     \
    }

// ---- prepass: K-fragment image + V-fragment image (V identical to R12's
// verified image; K re-addressed to fragment blocks, content unchanged) ----
__global__ __launch_bounds__(256) void prep_kv(const float* __restrict__ x2,
                                               unsigned char* __restrict__ wsK,
                                               unsigned char* __restrict__ wsV) {
    __shared__ unsigned short lt[128 * 34];    // 8704 B, row stride 68 B
    const int blk = blockIdx.x;                // 32 bh x 64 tiles
    const int bh = blk >> 6, kt = blk & 63;
    const int t = threadIdx.x;
    const int r = t >> 3, dc = t & 7;          // k-row, 16-wide d-chunk
    const float* src = x2 + ((size_t)bh * SK + (size_t)(kt * 32 + r)) * DD + dc * 16;
    float4 a0 = *(const float4*)(src);
    float4 a1 = *(const float4*)(src + 4);
    float4 a2 = *(const float4*)(src + 8);
    float4 a3 = *(const float4*)(src + 12);
    u32x4 w0, w1;
    w0[0]=pk_bf16(a0.x,a0.y); w0[1]=pk_bf16(a0.z,a0.w);
    w0[2]=pk_bf16(a1.x,a1.y); w0[3]=pk_bf16(a1.z,a1.w);
    w1[0]=pk_bf16(a2.x,a2.y); w1[1]=pk_bf16(a2.z,a2.w);
    w1[2]=pk_bf16(a3.x,a3.y); w1[3]=pk_bf16(a3.z,a3.w);
    // K fragment image: frag f = (d>>5)*2 + (r>>4); lane slot c*64 + g*16.
    // thread's w0 -> g0 = (2dc)&3, w1 -> g0+1 (adjacent 16B)
    {
        const int f  = (dc >> 1) * 2 + (r >> 4);
        const int a  = f * 1024 + (r & 15) * 64 + ((2 * dc) & 3) * 16;
        unsigned char* dstK = wsK + ((size_t)bh * 64 + kt) * KIMG + a;
        *(u32x4*)(dstK)      = w0;
        *(u32x4*)(dstK + 16) = w1;
    }
    // V fragment image via LDS transpose, permuted slot (R12-verified)
    const int tt = r & 15;
    const int s = 8*(tt>>2) + 4*(r>>4) + (tt&3);
#pragma unroll
    for (int i = 0; i < 4; ++i) {
        unsigned int u = w0[i];
        lt[(dc*16 + 2*i    ) * 34 + s] = (unsigned short)(u & 0xffffu);
        lt[(dc*16 + 2*i + 1) * 34 + s] = (unsigned short)(u >> 16);
    }
#pragma unroll
    for (int i = 0; i < 4; ++i) {
        unsigned int u = w1[i];
        lt[(dc*16 + 8 + 2*i    ) * 34 + s] = (unsigned short)(u & 0xffffu);
        lt[(dc*16 + 8 + 2*i + 1) * 34 + s] = (unsigned short)(u >> 16);
    }
    __syncthreads();
    const int d = t >> 1, h = t & 1;
    const unsigned int* lrow = (const unsigned int*)((const unsigned char*)lt + d*68 + h*32);
    u32x4 o0, o1;
    o0[0]=lrow[0]; o0[1]=lrow[1]; o0[2]=lrow[2]; o0[3]=lrow[3];
    o1[0]=lrow[4]; o1[1]=lrow[5]; o1[2]=lrow[6]; o1[3]=lrow[7];
    unsigned char* dstV = wsV + ((size_t)bh*64 + kt) * KIMG + d*64 + h*32;
    *(u32x4*)(dstV)      = o0;
    *(u32x4*)(dstV + 16) = o1;
}

__global__ __launch_bounds__(256, 3) void fattn_bf16(
    const float* __restrict__ x1, const unsigned char* __restrict__ wsK,
    const unsigned char* __restrict__ wsV,
    const float* __restrict__ mask, float* __restrict__ out)
{
    KERNEL_PRE()
    const unsigned char* kbase = wsK + (size_t)bh * 64 * KIMG + c * 64 + g * 16;
    const unsigned char* vbase = wsV + (size_t)bh * 64 * KIMG + c * 64 + g * 16;

    // prologue: issue kf(0) + mask(0); latency covered by Q load/convert
    short8 kf[8], vf[8];
#pragma unroll
    for (int f = 0; f < 8; ++f)
        kf[f] = *(const short8*)(kbase + f * 1024);
    float4 mA0 = *(const float4*)(mq0);
    float4 mA1 = *(const float4*)(mq0 + 16);
    float4 mB0, mB1;

    KERNEL_QLOAD()

    f32x4 o[8] = {};
    float lp = 0.f;

    for (int kt2 = 0; kt2 < NKT / 2; ++kt2) {
        BODY_BF(mA0, mA1, mB0, mB1, 2*kt2)
        BODY_BF(mB0, mB1, mA0, mA1, 2*kt2 + 1)
    }
    KERNEL_EPILOGUE()
}

// -------- fp32 fallback (R9-proven kernel, unchanged) --------
#define BODY_F32(KC0,KC1,KC2,KC3, VC0,VC1,VC2,VC3, MC0,MC1,                    \
                 KN0,KN1,KN2,KN3, VN0,VN1,VN2,VN3, MN0,MN1, KT)                \
  { const int kbn = ((KT) < NKT - 1) ? ((KT) + 1) * KBLK : (KT) * KBLK;        \
    KN0 = *(const float4*)(x2fb + (size_t)(kbn + kkf)      * DD + kd0);        \
    KN1 = *(const float4*)(x2fb + (size_t)(kbn + kkf)      * DD + kd0 + 4);    \
    KN2 = *(const float4*)(x2fb + (size_t)(kbn + kkf + 16) * DD + kd0);        \
    KN3 = *(const float4*)(x2fb + (size_t)(kbn + kkf + 16) * DD + kd0 + 4);    \
    VN0 = *(const float4*)(x2fb + (size_t)(kbn + 2*kp)     * DD + vdb);        \
    VN1 = *(const float4*)(x2fb + (size_t)(kbn + 2*kp)     * DD + vdb + 4);    \
    VN2 = *(const float4*)(x2fb + (size_t)(kbn + 2*kp + 1) * DD + vdb);        \
    VN3 = *(const float4*)(x2fb + (size_t)(kbn + 2*kp + 1) * DD + vdb + 4);    \
    MN0 = *(const float4*)(mq0 + kbn);                                         \
    MN1 = *(const float4*)(mq0 + kbn + 16);                                    \
    { union { unsigned int u[4]; short8 s; } k0_, k1_;                         \
      k0_.u[0]=pk_bf16(KC0.x,KC0.y); k0_.u[1]=pk_bf16(KC0.z,KC0.w);            \
      k0_.u[2]=pk_bf16(KC1.x,KC1.y); k0_.u[3]=pk_bf16(KC1.z,KC1.w);            \
      k1_.u[0]=pk_bf16(KC2.x,KC2.y); k1_.u[1]=pk_bf16(KC2.z,KC2.w);            \
      k1_.u[2]=pk_bf16(KC3.x,KC3.y); k1_.u[3]=pk_bf16(KC3.z,KC3.w);            \
      *(short8*)(smem + (kkf)      * KPITCH + 2*kd0) = k0_.s;                  \
      *(short8*)(smem + (kkf + 16) * KPITCH + 2*kd0) = k1_.s; }                \
    *(unsigned int*)(smem + VOFF_F + (vdb+0)*VPITCH + 4*kp) = pk_bf16(VC0.x, VC2.x); \
    *(unsigned int*)(smem + VOFF_F + (vdb+1)*VPITCH + 4*kp) = pk_bf16(VC0.y, VC2.y); \
    *(unsigned int*)(smem + VOFF_F + (vdb+2)*VPITCH + 4*kp) = pk_bf16(VC0.z, VC2.z); \
    *(unsigned int*)(smem + VOFF_F + (vdb+3)*VPITCH + 4*kp) = pk_bf16(VC0.w, VC2.w); \
    *(unsigned int*)(smem + VOFF_F + (vdb+4)*VPITCH + 4*kp) = pk_bf16(VC1.x, VC3.x); \
    *(unsigned int*)(smem + VOFF_F + (vdb+5)*VPITCH + 4*kp) = pk_bf16(VC1.y, VC3.y); \
    *(unsigned int*)(smem + VOFF_F + (vdb+6)*VPITCH + 4*kp) = pk_bf16(VC1.z, VC3.z); \
    *(unsigned int*)(smem + VOFF_F + (vdb+7)*VPITCH + 4*kp) = pk_bf16(VC1.w, VC3.w); \
    BAR()                                                                      \
    f32x4 s00={0,0,0,0}, s01={0,0,0,0};                                        \
    _Pragma("unroll")                                                          \
    for (int ks = 0; ks < 4; ++ks) {                                           \
      short8 ka0 = *(const short8*)(smem + (c)      * KPITCH + ks*64 + 16*g);  \
      short8 ka1 = *(const short8*)(smem + (16 + c) * KPITCH + ks*64 + 16*g);  \
      s00 = __builtin_amdgcn_mfma_f32_16x16x32_bf16(ka0, qf[ks], s00, 0,0,0);  \
      s01 = __builtin_amdgcn_mfma_f32_16x16x32_bf16(ka1, qf[ks], s01, 0,0,0);  \
    }                                                                          \
    short8 pa;                                                                 \
    SOFTMAX_PACK(pa, s00, s01, MC0, MC1, lp)                                   \
    _Pragma("unroll")                                                          \
    for (int d8 = 0; d8 < 8; ++d8) {                                           \
      short8 vv = *(const short8*)(smem + VOFF_F + (d8*16 + c)*VPITCH + 16*g); \
      o[d8] = __builtin_amdgcn_mfma_f32_16x16x32_bf16(pa, vv, o[d8], 0,0,0);   \
    }                                                                          \
    BAR()                                                                      \
  }

__global__ __launch_bounds__(256, 3) void fattn_f32(
    const float* __restrict__ x1, const float* __restrict__ x2,
    const float* __restrict__ mask, float* __restrict__ out)
{
    __shared__ __align__(16) unsigned char smem[SMEM_F32];
    KERNEL_PRE()
    const int sA = c + ((g & 1) << 5);
    const int sB = sA + 16;
    const bool hi = (g >= 2);
    const float* x2fb = x2 + (size_t)bh * SK * DD;
    const int kkf = tid >> 4, kd0 = (tid & 15) * 8;
    const int kp  = tid & 15, vdb = (tid >> 4) * 8;

    float4 kA0 = *(const float4*)(x2fb + (size_t)(kkf)      * DD + kd0);
    float4 kA1 = *(const float4*)(x2fb + (size_t)(kkf)      * DD + kd0 + 4);
    float4 kA2 = *(const float4*)(x2fb + (size_t)(kkf + 16) * DD + kd0);
    float4 kA3 = *(const float4*)(x2fb + (size_t)(kkf + 16) * DD + kd0 + 4);
    float4 vA0 = *(const float4*)(x2fb + (size_t)(2*kp)     * DD + vdb);
    float4 vA1 = *(const float4*)(x2fb + (size_t)(2*kp)     * DD + vdb + 4);
    float4 vA2 = *(const float4*)(x2fb + (size_t)(2*kp + 1) * DD + vdb);
    float4 vA3 = *(const float4*)(x2fb + (size_t)(2*kp + 1) * DD + vdb + 4);
    float4 mA0 = *(const float4*)(mq0);
    float4 mA1 = *(const float4*)(mq0 + 16);
    float4 kB0,kB1,kB2,kB3, vB0,vB1,vB2,vB3, mB0,mB1;

    KERNEL_QLOAD()

    f32x4 o[8] = {};
    float lp = 0.f;

    for (int kt2 = 0; kt2 < NKT / 2; ++kt2) {
        BODY_F32(kA0,kA1,kA2,kA3, vA0,vA1,vA2,vA3, mA0,mA1,
                 kB0,kB1,kB2,kB3, vB0,vB1,vB2,vB3, mB0,mB1, 2*kt2)
        BODY_F32(kB0,kB1,kB2,kB3, vB0,vB1,vB2,vB3, mB0,mB1,
                 kA0,kA1,kA2,kA3, vA0,vA1,vA2,vA3, mA0,mA1, 2*kt2 + 1)
    }
    KERNEL_EPILOGUE()
}

extern "C" void kernel_launch(void* const* d_in, const int* in_sizes, int n_in,
                              void* d_out, int out_size, void* d_ws, size_t ws_size,
                              hipStream_t stream) {
    const float* x1   = (const float*)d_in[0];
    const float* x2   = (const float*)d_in[1];
    const float* mask = (const float*)d_in[2];
    float* out = (float*)d_out;
    const size_t szK = (size_t)NBH * 64 * KIMG;            // 16.78 MB
    const size_t szV = (size_t)NBH * 64 * KIMG;            // 16.78 MB
    if (ws_size >= szK + szV) {
        unsigned char* wsK = (unsigned char*)d_ws;
        unsigned char* wsV = wsK + szK;
        prep_kv<<<dim3(NBH * 64), dim3(256), 0, stream>>>(x2, wsK, wsV);
        fattn_bf16<<<dim3(NBH * (SQ / QBLK)), dim3(256), 0, stream>>>(
            x1, wsK, wsV, mask, out);
    } else {
        fattn_f32<<<dim3(NBH * (SQ / QBLK)), dim3(256), 0, stream>>>(x1, x2, mask, out);
    }
}

// Round 14
// 188.782 us; speedup vs baseline: 1.7226x; 1.7226x over previous
//
#include <hip/hip_runtime.h>
#include <hip/hip_bf16.h>

#define SQ 2048
#define SK 2048
#define DD 128
#define NBH 32
#define QBLK 64
#define KBLK 32
#define NKT (SK / KBLK)
#define SCALE 0.20884964425119185f
#define SCL2 (SCALE * 1.4426950408889634f)   // fold log2(e): exp2

typedef __attribute__((ext_vector_type(8))) short short8;
typedef __attribute__((ext_vector_type(4))) float f32x4;
typedef __attribute__((ext_vector_type(4))) unsigned int u32x4;

// bf16 path LDS: K-image dbuf (2x8KB) at 0, V-image dbuf (2x8KB) at 16384
#define KIMG 8192
#define SMEM_BF 32768
// f32 fallback LDS (R9-proven layout)
#define KPITCH 272
#define VPITCH 80
#define VOFF_F 8704
#define SMEM_F32 18944

#define GLDS(G, L) __builtin_amdgcn_global_load_lds( \
    (const __attribute__((address_space(1))) unsigned int*)(G), \
    (__attribute__((address_space(3))) unsigned int*)(L), 16, 0, 0)

static __device__ __forceinline__ unsigned int pk_bf16(float lo, float hi) {
    float2 f2; f2.x = lo; f2.y = hi;
    __hip_bfloat162 h = __float22bfloat162_rn(f2);   // v_cvt_pk_bf16_f32
    union { __hip_bfloat162 h2; unsigned int u; } cv; cv.h2 = h;
    return cv.u;
}

// natural-order softmax (R12-verified): P feeds PV A-operand directly
// (k-permutation baked into the V image; MFMA k-sum is permutation-invariant)
#define SOFTMAX_NAT(PA, SA_, SB_, MCa, MCb, LPART)                             \
  { float p_[8];                                                               \
    p_[0] = __builtin_amdgcn_exp2f(SA_[0]*SCL2);                               \
    p_[1] = __builtin_amdgcn_exp2f(SA_[1]*SCL2);                               \
    p_[2] = __builtin_amdgcn_exp2f(SA_[2]*SCL2);                               \
    p_[3] = __builtin_amdgcn_exp2f(SA_[3]*SCL2);                               \
    p_[4] = __builtin_amdgcn_exp2f(SB_[0]*SCL2);                               \
    p_[5] = __builtin_amdgcn_exp2f(SB_[1]*SCL2);                               \
    p_[6] = __builtin_amdgcn_exp2f(SB_[2]*SCL2);                               \
    p_[7] = __builtin_amdgcn_exp2f(SB_[3]*SCL2);                               \
    LPART += ((p_[0]+p_[1]) + (p_[2]+p_[3])) + ((p_[4]+p_[5]) + (p_[6]+p_[7]));\
    p_[0]*=MCa.x; p_[1]*=MCa.y; p_[2]*=MCa.z; p_[3]*=MCa.w;                    \
    p_[4]*=MCb.x; p_[5]*=MCb.y; p_[6]*=MCb.z; p_[7]*=MCb.w;                    \
    union { unsigned int u[4]; short8 v; } pb_;                                \
    pb_.u[0] = pk_bf16(p_[0],p_[1]); pb_.u[1] = pk_bf16(p_[2],p_[3]);          \
    pb_.u[2] = pk_bf16(p_[4],p_[5]); pb_.u[3] = pk_bf16(p_[6],p_[7]);          \
    PA = pb_.v; }

// f32 fallback keeps the shfl-redistribution (R3..R9-proven)
#define SOFTMAX_PACK(PA, SA_, SB_, MCa, MCb, LPART)                            \
  { float p_[8];                                                               \
    p_[0] = __builtin_amdgcn_exp2f(SA_[0]*SCL2);                               \
    p_[1] = __builtin_amdgcn_exp2f(SA_[1]*SCL2);                               \
    p_[2] = __builtin_amdgcn_exp2f(SA_[2]*SCL2);                               \
    p_[3] = __builtin_amdgcn_exp2f(SA_[3]*SCL2);                               \
    p_[4] = __builtin_amdgcn_exp2f(SB_[0]*SCL2);                               \
    p_[5] = __builtin_amdgcn_exp2f(SB_[1]*SCL2);                               \
    p_[6] = __builtin_amdgcn_exp2f(SB_[2]*SCL2);                               \
    p_[7] = __builtin_amdgcn_exp2f(SB_[3]*SCL2);                               \
    LPART += ((p_[0]+p_[1]) + (p_[2]+p_[3])) + ((p_[4]+p_[5]) + (p_[6]+p_[7]));\
    p_[0]*=MCa.x; p_[1]*=MCa.y; p_[2]*=MCa.z; p_[3]*=MCa.w;                    \
    p_[4]*=MCb.x; p_[5]*=MCb.y; p_[6]*=MCb.z; p_[7]*=MCb.w;                    \
    unsigned int P0 = pk_bf16(p_[0],p_[1]), P1 = pk_bf16(p_[2],p_[3]);         \
    unsigned int P2 = pk_bf16(p_[4],p_[5]), P3 = pk_bf16(p_[6],p_[7]);         \
    unsigned int a0 = __shfl((int)P0, sA), a2 = __shfl((int)P2, sA);           \
    unsigned int b0 = __shfl((int)P1, sA), b2 = __shfl((int)P3, sA);           \
    unsigned int c0 = __shfl((int)P0, sB), c2 = __shfl((int)P2, sB);           \
    unsigned int d0 = __shfl((int)P1, sB), d2 = __shfl((int)P3, sB);           \
    union { unsigned int u[4]; short8 v; } pb_;                                \
    pb_.u[0] = hi ? a2 : a0; pb_.u[1] = hi ? b2 : b0;                          \
    pb_.u[2] = hi ? c2 : c0; pb_.u[3] = hi ? d2 : d0;                          \
    PA = pb_.v; }

#define BAR()                                                                  \
    asm volatile("s_waitcnt lgkmcnt(0)" ::: "memory");                         \
    __builtin_amdgcn_sched_barrier(0);                                         \
    __builtin_amdgcn_s_barrier();                                              \
    __builtin_amdgcn_sched_barrier(0);

// one K-tile: glds K/V(t+1)->other buf | fence | mask(t+1) | QK | softmax |
// PV | fence | vmcnt(2): glds landed, masks stay in flight | barrier
#define BODY_BF(CUR, OTH, MC0, MC1, MN0, MN1, KT)                              \
  { const int ktn = ((KT) < NKT - 1) ? (KT) + 1 : (KT);                        \
    const unsigned char* gK = wsKb + (size_t)ktn * KIMG + tid * 16;            \
    const unsigned char* gV = wsVb + (size_t)ktn * KIMG + tid * 16;            \
    GLDS(gK,        smem + (OTH)*KIMG + (wid << 10));                          \
    GLDS(gK + 4096, smem + (OTH)*KIMG + 4096 + (wid << 10));                   \
    GLDS(gV,        smem + 16384 + (OTH)*KIMG + (wid << 10));                  \
    GLDS(gV + 4096, smem + 16384 + (OTH)*KIMG + 4096 + (wid << 10));           \
    __builtin_amdgcn_sched_barrier(0);   /* glds issued before masks */        \
    MN0 = *(const float4*)(mq0 + ktn * KBLK);                                  \
    MN1 = *(const float4*)(mq0 + ktn * KBLK + 16);                             \
    f32x4 s00 = {0,0,0,0}, s01 = {0,0,0,0};                                    \
    __builtin_amdgcn_s_setprio(1);                                             \
    _Pragma("unroll")                                                          \
    for (int ks = 0; ks < 4; ++ks) {                                           \
      short8 ka0 = *(const short8*)(smem + (CUR)*KIMG + (2*ks)*1024 + lb);     \
      short8 ka1 = *(const short8*)(smem + (CUR)*KIMG + (2*ks+1)*1024 + lb);   \
      s00 = __builtin_amdgcn_mfma_f32_16x16x32_bf16(ka0, qf[ks], s00, 0,0,0);  \
      s01 = __builtin_amdgcn_mfma_f32_16x16x32_bf16(ka1, qf[ks], s01, 0,0,0);  \
    }                                                                          \
    __builtin_amdgcn_s_setprio(0);                                             \
    short8 pa;                                                                 \
    SOFTMAX_NAT(pa, s00, s01, MC0, MC1, lp)                                    \
    __builtin_amdgcn_s_setprio(1);                                             \
    _Pragma("unroll")                                                          \
    for (int d8 = 0; d8 < 8; ++d8) {                                           \
      short8 vv = *(const short8*)(smem + 16384 + (CUR)*KIMG + d8*1024 + lb);  \
      o[d8] = __builtin_amdgcn_mfma_f32_16x16x32_bf16(pa, vv, o[d8], 0,0,0);   \
    }                                                                          \
    __builtin_amdgcn_s_setprio(0);                                             \
    __builtin_amdgcn_sched_barrier(0);                                         \
    asm volatile("s_waitcnt vmcnt(2)" ::: "memory");                           \
    __builtin_amdgcn_sched_barrier(0);                                         \
    __builtin_amdgcn_s_barrier();                                              \
    __builtin_amdgcn_sched_barrier(0);                                         \
  }

#define KERNEL_PRE(SMEMSZ)                                                     \
    __shared__ __align__(16) unsigned char smem[SMEMSZ];                       \
    const int tid  = threadIdx.x;                                              \
    const int lane = tid & 63, wid = tid >> 6;                                 \
    const int c = lane & 15, g = lane >> 4;                                    \
    const int lb = lane * 16;                                                  \
    const int bid = blockIdx.x;                                                \
    const int swz = (bid & 7) * 128 + (bid >> 3);  /* 1024 = 128 x 8 */        \
    const int bh = swz >> 5;                                                   \
    const int qb = swz & 31;                                                   \
    const float* x1b = x1 + ((size_t)bh * SQ + (size_t)qb * QBLK) * DD;        \
    const float* mb  = mask + ((size_t)bh * SQ + (size_t)qb * QBLK) * SK;      \
    float*      outb = out + ((size_t)bh * SQ + (size_t)qb * QBLK) * DD;       \
    const int sA = c + ((g & 1) << 5);                                         \
    const int sB = sA + 16;                                                    \
    const bool hi = (g >= 2);                                                  \
    const float* mq0 = mb + (size_t)(wid*16 + c) * SK + 4*g;                   \
    (void)sA; (void)sB; (void)hi; (void)lb;

#define KERNEL_QLOAD()                                                         \
    short8 qf[4];                                                              \
    {  const float* q0r = x1b + (size_t)(wid*16 + c) * DD;                     \
       _Pragma("unroll")                                                       \
       for (int ks = 0; ks < 4; ++ks) {                                        \
           float4 a = *(const float4*)(q0r + ks*32 + 8*g);                     \
           float4 b = *(const float4*)(q0r + ks*32 + 8*g + 4);                 \
           union { unsigned int u[4]; short8 s; } t;                           \
           t.u[0]=pk_bf16(a.x,a.y); t.u[1]=pk_bf16(a.z,a.w);                   \
           t.u[2]=pk_bf16(b.x,b.y); t.u[3]=pk_bf16(b.z,b.w);                   \
           qf[ks]=t.s;                                                         \
       } }

#define KERNEL_EPILOGUE()                                                      \
    float l = lp; l += __shfl_xor(l, 16); l += __shfl_xor(l, 32);              \
    float il0 = 1.0f/__shfl(l, 4*g+0), il1 = 1.0f/__shfl(l, 4*g+1);            \
    float il2 = 1.0f/__shfl(l, 4*g+2), il3 = 1.0f/__shfl(l, 4*g+3);            \
    float* orow = outb + (size_t)(wid*16) * DD;                                \
    _Pragma("unroll")                                                          \
    for (int d8 = 0; d8 < 8; ++d8) {                                           \
        orow[(4*g + 0) * DD + d8*16 + c] = o[d8][0] * il0;                     \
        orow[(4*g + 1) * DD + d8*16 + c] = o[d8][1] * il1;                     \
        orow[(4*g + 2) * DD + d8*16 + c] = o[d8][2] * il2;                     \
        orow[(4*g + 3) * DD + d8*16 + c] = o[d8][3] * il3;                     \
    }

// ---- prepass: lane-linear fragment images. Unit of lane l=16g+c sits at
// byte f*1024 + l*16 (f = fragment index). Content identical to R12-verified
// fragments; only addressing changed.
__global__ __launch_bounds__(256) void prep_kv(const float* __restrict__ x2,
                                               unsigned char* __restrict__ wsK,
                                               unsigned char* __restrict__ wsV) {
    __shared__ unsigned short lt[128 * 34];    // 8704 B, row stride 68 B
    const int blk = blockIdx.x;                // 32 bh x 64 tiles
    const int bh = blk >> 6, kt = blk & 63;
    const int t = threadIdx.x;
    const int r = t >> 3, dc = t & 7;          // k-row, 16-wide d-chunk
    const float* src = x2 + ((size_t)bh * SK + (size_t)(kt * 32 + r)) * DD + dc * 16;
    float4 a0 = *(const float4*)(src);
    float4 a1 = *(const float4*)(src + 4);
    float4 a2 = *(const float4*)(src + 8);
    float4 a3 = *(const float4*)(src + 12);
    u32x4 w0, w1;
    w0[0]=pk_bf16(a0.x,a0.y); w0[1]=pk_bf16(a0.z,a0.w);
    w0[2]=pk_bf16(a1.x,a1.y); w0[3]=pk_bf16(a1.z,a1.w);
    w1[0]=pk_bf16(a2.x,a2.y); w1[1]=pk_bf16(a2.z,a2.w);
    w1[2]=pk_bf16(a3.x,a3.y); w1[3]=pk_bf16(a3.z,a3.w);
    // K image: f = 2*ks + rh; unit (c=r&15, g) at f*1024 + (16g+c)*16.
    // w0 -> g0 = 2*(dc&1) (d = ks*32 + 8*g0 ...), w1 -> g0+1
    {
        const int ks = dc >> 1, rh = r >> 4, f = 2*ks + rh;
        const int cl = r & 15, g0 = 2 * (dc & 1);
        unsigned char* dstK = wsK + ((size_t)bh * 64 + kt) * KIMG + f * 1024 + cl * 16;
        *(u32x4*)(dstK + (g0)     * 256) = w0;
        *(u32x4*)(dstK + (g0 + 1) * 256) = w1;
    }
    // V image via LDS transpose, permuted slot (R12-verified formula)
    const int tt = r & 15;
    const int s = 8*(tt>>2) + 4*(r>>4) + (tt&3);
#pragma unroll
    for (int i = 0; i < 4; ++i) {
        unsigned int u = w0[i];
        lt[(dc*16 + 2*i    ) * 34 + s] = (unsigned short)(u & 0xffffu);
        lt[(dc*16 + 2*i + 1) * 34 + s] = (unsigned short)(u >> 16);
    }
#pragma unroll
    for (int i = 0; i < 4; ++i) {
        unsigned int u = w1[i];
        lt[(dc*16 + 8 + 2*i    ) * 34 + s] = (unsigned short)(u & 0xffffu);
        lt[(dc*16 + 8 + 2*i + 1) * 34 + s] = (unsigned short)(u >> 16);
    }
    __syncthreads();
    const int d = t >> 1, h = t & 1;
    const int d8 = d >> 4, cl = d & 15;
    const unsigned int* lrow = (const unsigned int*)((const unsigned char*)lt + d*68 + h*32);
    u32x4 o0, o1;
    o0[0]=lrow[0]; o0[1]=lrow[1]; o0[2]=lrow[2]; o0[3]=lrow[3];
    o1[0]=lrow[4]; o1[1]=lrow[5]; o1[2]=lrow[6]; o1[3]=lrow[7];
    // unit (cl, g=2h) -> d8*1024 + (16*(2h)+cl)*16 ; g=2h+1 -> +256
    unsigned char* dstV = wsV + ((size_t)bh*64 + kt) * KIMG + d8*1024
                        + (2*h)*256 + cl*16;
    *(u32x4*)(dstV)       = o0;
    *(u32x4*)(dstV + 256) = o1;
}

__global__ __launch_bounds__(256, 4) void fattn_bf16(
    const float* __restrict__ x1, const unsigned char* __restrict__ wsK,
    const unsigned char* __restrict__ wsV,
    const float* __restrict__ mask, float* __restrict__ out)
{
    KERNEL_PRE(SMEM_BF)
    const unsigned char* wsKb = wsK + (size_t)bh * 64 * KIMG;
    const unsigned char* wsVb = wsV + (size_t)bh * 64 * KIMG;

    // prologue: stage tile 0, load mask(0), Q fragments, full drain once
    GLDS(wsKb + tid * 16,        smem + (wid << 10));
    GLDS(wsKb + 4096 + tid * 16, smem + 4096 + (wid << 10));
    GLDS(wsVb + tid * 16,        smem + 16384 + (wid << 10));
    GLDS(wsVb + 4096 + tid * 16, smem + 16384 + 4096 + (wid << 10));
    float4 mA0 = *(const float4*)(mq0);
    float4 mA1 = *(const float4*)(mq0 + 16);
    float4 mB0, mB1;
    KERNEL_QLOAD()
    asm volatile("s_waitcnt vmcnt(0)" ::: "memory");
    __builtin_amdgcn_sched_barrier(0);
    __builtin_amdgcn_s_barrier();
    __builtin_amdgcn_sched_barrier(0);

    f32x4 o[8] = {};
    float lp = 0.f;

    for (int kt2 = 0; kt2 < NKT / 2; ++kt2) {
        BODY_BF(0, 1, mA0, mA1, mB0, mB1, 2*kt2)
        BODY_BF(1, 0, mB0, mB1, mA0, mA1, 2*kt2 + 1)
    }
    KERNEL_EPILOGUE()
}

// -------- fp32 fallback (R9-proven kernel, unchanged) --------
#define BODY_F32(KC0,KC1,KC2,KC3, VC0,VC1,VC2,VC3, MC0,MC1,                    \
                 KN0,KN1,KN2,KN3, VN0,VN1,VN2,VN3, MN0,MN1, KT)                \
  { const int kbn = ((KT) < NKT - 1) ? ((KT) + 1) * KBLK : (KT) * KBLK;        \
    KN0 = *(const float4*)(x2fb + (size_t)(kbn + kkf)      * DD + kd0);        \
    KN1 = *(const float4*)(x2fb + (size_t)(kbn + kkf)      * DD + kd0 + 4);    \
    KN2 = *(const float4*)(x2fb + (size_t)(kbn + kkf + 16) * DD + kd0);        \
    KN3 = *(const float4*)(x2fb + (size_t)(kbn + kkf + 16) * DD + kd0 + 4);    \
    VN0 = *(const float4*)(x2fb + (size_t)(kbn + 2*kp)     * DD + vdb);        \
    VN1 = *(const float4*)(x2fb + (size_t)(kbn + 2*kp)     * DD + vdb + 4);    \
    VN2 = *(const float4*)(x2fb + (size_t)(kbn + 2*kp + 1) * DD + vdb);        \
    VN3 = *(const float4*)(x2fb + (size_t)(kbn + 2*kp + 1) * DD + vdb + 4);    \
    MN0 = *(const float4*)(mq0 + kbn);                                         \
    MN1 = *(const float4*)(mq0 + kbn + 16);                                    \
    { union { unsigned int u[4]; short8 s; } k0_, k1_;                         \
      k0_.u[0]=pk_bf16(KC0.x,KC0.y); k0_.u[1]=pk_bf16(KC0.z,KC0.w);            \
      k0_.u[2]=pk_bf16(KC1.x,KC1.y); k0_.u[3]=pk_bf16(KC1.z,KC1.w);            \
      k1_.u[0]=pk_bf16(KC2.x,KC2.y); k1_.u[1]=pk_bf16(KC2.z,KC2.w);            \
      k1_.u[2]=pk_bf16(KC3.x,KC3.y); k1_.u[3]=pk_bf16(KC3.z,KC3.w);            \
      *(short8*)(smem + (kkf)      * KPITCH + 2*kd0) = k0_.s;                  \
      *(short8*)(smem + (kkf + 16) * KPITCH + 2*kd0) = k1_.s; }                \
    *(unsigned int*)(smem + VOFF_F + (vdb+0)*VPITCH + 4*kp) = pk_bf16(VC0.x, VC2.x); \
    *(unsigned int*)(smem + VOFF_F + (vdb+1)*VPITCH + 4*kp) = pk_bf16(VC0.y, VC2.y); \
    *(unsigned int*)(smem + VOFF_F + (vdb+2)*VPITCH + 4*kp) = pk_bf16(VC0.z, VC2.z); \
    *(unsigned int*)(smem + VOFF_F + (vdb+3)*VPITCH + 4*kp) = pk_bf16(VC0.w, VC2.w); \
    *(unsigned int*)(smem + VOFF_F + (vdb+4)*VPITCH + 4*kp) = pk_bf16(VC1.x, VC3.x); \
    *(unsigned int*)(smem + VOFF_F + (vdb+5)*VPITCH + 4*kp) = pk_bf16(VC1.y, VC3.y); \
    *(unsigned int*)(smem + VOFF_F + (vdb+6)*VPITCH + 4*kp) = pk_bf16(VC1.z, VC3.z); \
    *(unsigned int*)(smem + VOFF_F + (vdb+7)*VPITCH + 4*kp) = pk_bf16(VC1.w, VC3.w); \
    BAR()                                                                      \
    f32x4 s00={0,0,0,0}, s01={0,0,0,0};                                        \
    _Pragma("unroll")                                                          \
    for (int ks = 0; ks < 4; ++ks) {                                           \
      short8 ka0 = *(const short8*)(smem + (c)      * KPITCH + ks*64 + 16*g);  \
      short8 ka1 = *(const short8*)(smem + (16 + c) * KPITCH + ks*64 + 16*g);  \
      s00 = __builtin_amdgcn_mfma_f32_16x16x32_bf16(ka0, qf[ks], s00, 0,0,0);  \
      s01 = __builtin_amdgcn_mfma_f32_16x16x32_bf16(ka1, qf[ks], s01, 0,0,0);  \
    }                                                                          \
    short8 pa;                                                                 \
    SOFTMAX_PACK(pa, s00, s01, MC0, MC1, lp)                                   \
    _Pragma("unroll")                                                          \
    for (int d8 = 0; d8 < 8; ++d8) {                                           \
      short8 vv = *(const short8*)(smem + VOFF_F + (d8*16 + c)*VPITCH + 16*g); \
      o[d8] = __builtin_amdgcn_mfma_f32_16x16x32_bf16(pa, vv, o[d8], 0,0,0);   \
    }                                                                          \
    BAR()                                                                      \
  }

__global__ __launch_bounds__(256, 3) void fattn_f32(
    const float* __restrict__ x1, const float* __restrict__ x2,
    const float* __restrict__ mask, float* __restrict__ out)
{
    KERNEL_PRE(SMEM_F32)
    const float* x2fb = x2 + (size_t)bh * SK * DD;
    const int kkf = tid >> 4, kd0 = (tid & 15) * 8;
    const int kp  = tid & 15, vdb = (tid >> 4) * 8;

    float4 kA0 = *(const float4*)(x2fb + (size_t)(kkf)      * DD + kd0);
    float4 kA1 = *(const float4*)(x2fb + (size_t)(kkf)      * DD + kd0 + 4);
    float4 kA2 = *(const float4*)(x2fb + (size_t)(kkf + 16) * DD + kd0);
    float4 kA3 = *(const float4*)(x2fb + (size_t)(kkf + 16) * DD + kd0 + 4);
    float4 vA0 = *(const float4*)(x2fb + (size_t)(2*kp)     * DD + vdb);
    float4 vA1 = *(const float4*)(x2fb + (size_t)(2*kp)     * DD + vdb + 4);
    float4 vA2 = *(const float4*)(x2fb + (size_t)(2*kp + 1) * DD + vdb);
    float4 vA3 = *(const float4*)(x2fb + (size_t)(2*kp + 1) * DD + vdb + 4);
    float4 mA0 = *(const float4*)(mq0);
    float4 mA1 = *(const float4*)(mq0 + 16);
    float4 kB0,kB1,kB2,kB3, vB0,vB1,vB2,vB3, mB0,mB1;

    KERNEL_QLOAD()

    f32x4 o[8] = {};
    float lp = 0.f;

    for (int kt2 = 0; kt2 < NKT / 2; ++kt2) {
        BODY_F32(kA0,kA1,kA2,kA3, vA0,vA1,vA2,vA3, mA0,mA1,
                 kB0,kB1,kB2,kB3, vB0,vB1,vB2,vB3, mB0,mB1, 2*kt2)
        BODY_F32(kB0,kB1,kB2,kB3, vB0,vB1,vB2,vB3, mB0,mB1,
                 kA0,kA1,kA2,kA3, vA0,vA1,vA2,vA3, mA0,mA1, 2*kt2 + 1)
    }
    KERNEL_EPILOGUE()
}

extern "C" void kernel_launch(void* const* d_in, const int* in_sizes, int n_in,
                              void* d_out, int out_size, void* d_ws, size_t ws_size,
                              hipStream_t stream) {
    const float* x1   = (const float*)d_in[0];
    const float* x2   = (const float*)d_in[1];
    const float* mask = (const float*)d_in[2];
    float* out = (float*)d_out;
    const size_t szK = (size_t)NBH * 64 * KIMG;            // 16.78 MB
    const size_t szV = (size_t)NBH * 64 * KIMG;            // 16.78 MB
    if (ws_size >= szK + szV) {
        unsigned char* wsK = (unsigned char*)d_ws;
        unsigned char* wsV = wsK + szK;
        prep_kv<<<dim3(NBH * 64), dim3(256), 0, stream>>>(x2, wsK, wsV);
        fattn_bf16<<<dim3(NBH * (SQ / QBLK)), dim3(256), 0, stream>>>(
            x1, wsK, wsV, mask, out);
    } else {
        fattn_f32<<<dim3(NBH * (SQ / QBLK)), dim3(256), 0, stream>>>(x1, x2, mask, out);
    }
}